// Round 5
// baseline (222.200 us; speedup 1.0000x reference)
//
#include <hip/hip_runtime.h>
#include <hip/hip_bf16.h>
#include <hip/hip_fp16.h>
#include <math.h>

#define BB   4
#define LL   4096
#define CCH  256
#define KK   7
#define HIDN 32
#define MTOT (BB * LL)          // 16384 rows
#define NOFF (CCH * KK)         // 1792
#define NP   4096               // padded fused N: col = g*16 + idx (0..6 off, 8..14 mask, 7/15 pad)

typedef __attribute__((ext_vector_type(8))) short short8;
typedef __attribute__((ext_vector_type(4))) short short4v;
typedef __attribute__((ext_vector_type(4))) float f32x4;
typedef __attribute__((address_space(1))) void gvoid_t;
typedef __attribute__((address_space(3))) void svoid_t;

#define CS_STRIDE 136           // ushorts per Cs row (128 cols + 8 pad, keeps 16B align)
#define XS_OFF    34816         // byte offset of Xs in lds (after Cs 128*136*2)
#define KW_OFF    37056         // Xs is 140*8*2 = 2240 B
#define RED_OFF   37312         // kws is 56 floats = 224 B (pad to 256)
#define LDS_TOTAL 38400

__device__ __forceinline__ float siluf(float v) { return v / (1.0f + expf(-v)); }
__device__ __forceinline__ float bf2f(ushort u) { unsigned x = (unsigned)u << 16; return __uint_as_float(x); }

// ---------------- precompute: env, kernel-net MLP (permuted), padded biases, accumulators ----------------
__global__ __launch_bounds__(256) void precompute_kernel(
    const float* __restrict__ raw_sigma,
    const float* __restrict__ k0w, const float* __restrict__ k0b,
    const float* __restrict__ k1w, const float* __restrict__ k1b,
    const float* __restrict__ k2w, const float* __restrict__ k2b,
    const float* __restrict__ k3w, const float* __restrict__ k3b,
    const float* __restrict__ b_off, const float* __restrict__ b_mask,
    float* __restrict__ kwp, float* __restrict__ bcomb,
    float* __restrict__ env, float* __restrict__ accum)
{
    __shared__ float h0[KK][HIDN];
    __shared__ float h1[KK][HIDN];
    __shared__ float h2[KK][HIDN];
    __shared__ float flatw[NOFF];
    __shared__ float envs[KK];
    int t = threadIdx.x;
    if (t < 2) accum[t] = 0.0f;
    if (t < KK * HIDN) {
        int k = t / HIDN, j = t % HIDN;
        float gk = -0.5f + (float)k * (1.0f / 6.0f);
        float v = gk * 30.0f * k0w[j] + k0b[j];
        h0[k][j] = siluf(v);
    }
    __syncthreads();
    if (t < KK * HIDN) {
        int k = t / HIDN, j = t % HIDN;
        float s = k1b[j];
        #pragma unroll
        for (int i = 0; i < HIDN; ++i) s += h0[k][i] * k1w[i * HIDN + j];
        h1[k][j] = siluf(s);
    }
    __syncthreads();
    if (t < KK * HIDN) {
        int k = t / HIDN, j = t % HIDN;
        float s = k2b[j];
        #pragma unroll
        for (int i = 0; i < HIDN; ++i) s += h1[k][i] * k2w[i * HIDN + j];
        h2[k][j] = siluf(s);
    }
    __syncthreads();
    for (int k = 0; k < KK; ++k) {
        float s = k3b[t];
        #pragma unroll
        for (int i = 0; i < HIDN; ++i) s += h2[k][i] * k3w[i * CCH + t];
        flatw[k * CCH + t] = s;   // flat kernel_weights (raw-reshape semantics)
    }
    if (t == 0) {
        float sp = log1pf(expf(raw_sigma[0]));
        sp = fminf(fmaxf(sp, 0.05f), 0.5f);
        float sg = fmaxf(sp, 1e-6f);
        float ev[KK]; float ssum = 0.0f;
        for (int k = 0; k < KK; ++k) {
            float gk = -0.5f + (float)k * (1.0f / 6.0f);
            float d = gk / sg;
            ev[k] = expf(-0.5f * d * d);
            ssum += ev[k];
        }
        ssum = fmaxf(ssum, 1e-8f);
        for (int k = 0; k < KK; ++k) { env[k] = ev[k] / ssum; envs[k] = ev[k] / ssum; }
    }
    __syncthreads();
    // kw[g,k] = flat[g*7+k]; plane layout [k][g] for staged read
    #pragma unroll
    for (int k = 0; k < KK; ++k) kwp[k * CCH + t] = flatw[t * KK + k];
    // padded combined bias: [g*16 + k] = b_off[g*7+k]; [g*16+8+k] = b_mask[g*7+k]*env[k]; pads 0
    #pragma unroll
    for (int k = 0; k < KK; ++k) {
        bcomb[t * 16 + k]     = b_off[t * KK + k];
        bcomb[t * 16 + 8 + k] = b_mask[t * KK + k] * envs[k];
    }
    bcomb[t * 16 + 7]  = 0.0f;
    bcomb[t * 16 + 15] = 0.0f;
}

// ---------------- prep: weights [K=256][N] fp32 -> [N'][K=256] bf16 ----------------
// tasks 0-2: plain transpose. task 3: w_off -> rows g*16+k. task 4: w_mask*env[k] -> rows g*16+8+k.
// task 5: zero pad rows g*16+7, g*16+15.
__global__ __launch_bounds__(256) void prep_kernel(
    const float* __restrict__ w_in, const float* __restrict__ dw2_w,
    const float* __restrict__ w_out, const float* __restrict__ w_off,
    const float* __restrict__ w_mask, const float* __restrict__ env,
    __hip_bfloat16* __restrict__ wtin, __hip_bfloat16* __restrict__ wtdw2,
    __hip_bfloat16* __restrict__ wtout, __hip_bfloat16* __restrict__ wtcomb)
{
    const int task = blockIdx.y;
    const int tid = threadIdx.x;
    if (task == 5) {
        if (blockIdx.x >= 64) return;
        unsigned u = blockIdx.x * 256 + tid;        // 16384 threads x 8 ushorts = 512 rows * 256
        unsigned row_sel = u >> 5, chunk = u & 31;
        unsigned g = row_sel >> 1, which = row_sel & 1;
        unsigned row = g * 16 + 7 + which * 8;
        short8 z = {};
        *(short8*)((ushort*)wtcomb + (size_t)row * 256 + chunk * 8) = z;
        return;
    }
    const float* src; __hip_bfloat16* dst; int N; int mode = 0;
    switch (task) {
        case 0: src = w_in;  dst = wtin;  N = 256;  break;
        case 1: src = dw2_w; dst = wtdw2; N = 256;  break;
        case 2: src = w_out; dst = wtout; N = 256;  break;
        case 3: src = w_off;  dst = wtcomb; N = NOFF; mode = 1; break;
        default: src = w_mask; dst = wtcomb; N = NOFF; mode = 2; break;
    }
    int ntiles = 4 * (N / 64);
    if (blockIdx.x >= (unsigned)ntiles) return;
    int tk = (blockIdx.x & 3) * 64;
    int tn = (blockIdx.x >> 2) * 64;
    __shared__ float t[64][65];
    #pragma unroll
    for (int i = 0; i < 16; ++i) {
        int e = i * 256 + tid, kk = e >> 6, nn = e & 63;
        t[kk][nn] = src[(size_t)(tk + kk) * N + tn + nn];
    }
    __syncthreads();
    #pragma unroll
    for (int i = 0; i < 16; ++i) {
        int e = i * 256 + tid, nn = e >> 6, kk = e & 63;
        int c = tn + nn;
        float v = t[kk][nn];
        int cp;
        if (mode == 0) cp = c;
        else {
            int g = c / KK, k = c % KK;
            cp = g * 16 + k + (mode == 2 ? 8 : 0);
            if (mode == 2) v *= env[k];
        }
        dst[(size_t)cp * 256 + tk + kk] = __float2bfloat16(v);
    }
}

// ---------------- fused: x -> bf16 copy AND depthwise conv3 + bias + SiLU -> bf16 ----------------
__global__ __launch_bounds__(256) void dwconv_conv_kernel(
    const float* __restrict__ x, const float* __restrict__ w1,
    const float* __restrict__ b1, __hip_bfloat16* __restrict__ xbf,
    __hip_bfloat16* __restrict__ h)
{
    size_t base = ((size_t)blockIdx.x * 256 + threadIdx.x) * 4;   // over B*L*C, 4 ch/thread
    int c = (int)(base & (CCH - 1));
    int l = (int)((base >> 8) & (LL - 1));
    float4 xm = *(const float4*)&x[base];
    float4 xl = make_float4(0.f, 0.f, 0.f, 0.f);
    float4 xr = make_float4(0.f, 0.f, 0.f, 0.f);
    if (l > 0)      xl = *(const float4*)&x[base - CCH];
    if (l < LL - 1) xr = *(const float4*)&x[base + CCH];
    float vm[4] = {xm.x, xm.y, xm.z, xm.w};
    float vl[4] = {xl.x, xl.y, xl.z, xl.w};
    float vr[4] = {xr.x, xr.y, xr.z, xr.w};
    ushort xo[4], ho[4];
    #pragma unroll
    for (int j = 0; j < 4; ++j) {
        int cc = c + j;
        float s = vm[j] * w1[cc * 3 + 1] + vl[j] * w1[cc * 3 + 0] + vr[j] * w1[cc * 3 + 2] + b1[cc];
        __hip_bfloat16 hb = __float2bfloat16(siluf(s));
        __hip_bfloat16 xb = __float2bfloat16(vm[j]);
        ho[j] = *(ushort*)&hb;
        xo[j] = *(ushort*)&xb;
    }
    *(short4v*)&xbf[base] = *(short4v*)xo;
    *(short4v*)&h[base]   = *(short4v*)ho;
}

// ---------------- bf16 MFMA GEMM: C[rows][N] = A[rows][256] @ Bt[N][256]^T + bias ----------------
template<int OUTBF>
__global__ __launch_bounds__(256) void gemm_bf16_k256(
    const __hip_bfloat16* __restrict__ A,
    const __hip_bfloat16* __restrict__ Bt,
    const float* __restrict__ bias,
    void* __restrict__ C, int N)
{
    __shared__ __align__(16) char lds[32768];
    char* As = lds;
    char* Bs = lds + 16384;
    const int tid = threadIdx.x, lane = tid & 63, w = tid >> 6;
    const int wr = w >> 1, wc = w & 1;
    const size_t m0 = (size_t)blockIdx.y * 128, n0 = (size_t)blockIdx.x * 128;

    const int srow = w * 32 + (lane >> 3);
    const int sgr  = (lane & 7) ^ ((lane >> 3) & 7);        // swizzled source granule
    const __hip_bfloat16* a_src = A  + (m0 + srow) * 256 + sgr * 8;
    const __hip_bfloat16* b_src = Bt + (n0 + srow) * 256 + sgr * 8;
    char* a_dst = As + (w * 32) * 128;
    char* b_dst = Bs + (w * 32) * 128;

    f32x4 acc[4][4] = {};

    for (int kt = 0; kt < 4; ++kt) {
        const int k0 = kt * 64;
        #pragma unroll
        for (int inst = 0; inst < 4; ++inst) {
            __builtin_amdgcn_global_load_lds((gvoid_t*)(a_src + k0 + (size_t)inst * 8 * 256),
                                             (svoid_t*)(a_dst + inst * 1024), 16, 0, 0);
            __builtin_amdgcn_global_load_lds((gvoid_t*)(b_src + k0 + (size_t)inst * 8 * 256),
                                             (svoid_t*)(b_dst + inst * 1024), 16, 0, 0);
        }
        __syncthreads();
        #pragma unroll
        for (int ks = 0; ks < 2; ++ks) {
            short8 a[4], b[4];
            #pragma unroll
            for (int i = 0; i < 4; ++i) {
                int mr = wr * 64 + i * 16 + (lane & 15);
                int gk = ks * 4 + (lane >> 4);
                a[i] = *(const short8*)(As + mr * 128 + ((gk ^ (mr & 7)) << 4));
                int nr = wc * 64 + i * 16 + (lane & 15);
                b[i] = *(const short8*)(Bs + nr * 128 + ((gk ^ (nr & 7)) << 4));
            }
            #pragma unroll
            for (int i = 0; i < 4; ++i)
                #pragma unroll
                for (int j = 0; j < 4; ++j)
                    acc[i][j] = __builtin_amdgcn_mfma_f32_16x16x32_bf16(a[i], b[j], acc[i][j], 0, 0, 0);
        }
        __syncthreads();
    }
    #pragma unroll
    for (int j = 0; j < 4; ++j) {
        int col = (int)n0 + wc * 64 + j * 16 + (lane & 15);
        float bb = bias[col];
        #pragma unroll
        for (int i = 0; i < 4; ++i) {
            size_t row0 = m0 + wr * 64 + i * 16 + ((lane >> 4) << 2);
            f32x4 v = acc[i][j];
            #pragma unroll
            for (int q = 0; q < 4; ++q) {
                float val = v[q] + bb;
                if (OUTBF) ((__hip_bfloat16*)C)[(row0 + q) * N + col] = __float2bfloat16(val);
                else       ((float*)C)[(row0 + q) * N + col] = val;
            }
        }
    }
}

// ---------------- fused: off|mask GEMM + tanh + gather + softmax + weighted sum ----------------
// Bt layout: row c' = g*16 + idx, idx 0..6 = off tap k, 8..14 = mask tap k (env-scaled), 7/15 = 0.
// Block: 128 rows x 128 cols (= 8 complete g-groups). Writes only out_pre + scalar partials.
__global__ __launch_bounds__(256) void gemm_fused_sample(
    const __hip_bfloat16* __restrict__ A,      // xdw [16384][256]
    const __hip_bfloat16* __restrict__ Bt,     // wtcomb [4096][256]
    const float* __restrict__ bias,            // bcomb [4096] (padded layout)
    const __hip_bfloat16* __restrict__ xproj,  // [4][4096][256]
    const float* __restrict__ kwp,             // [7][256]
    __hip_bfloat16* __restrict__ out_pre,
    float* __restrict__ accum)
{
    __shared__ __align__(16) char lds[LDS_TOTAL];
    char* As = lds;
    char* Bs = lds + 16384;
    const int tid = threadIdx.x, lane = tid & 63, w = tid >> 6;
    const int wr = w >> 1, wc = w & 1;
    const size_t m0 = (size_t)blockIdx.y * 128;
    const int n0 = blockIdx.x * 128;
    const int g0 = blockIdx.x * 8;
    const int l0 = (int)(m0 & (LL - 1));
    const int bidx = (int)(m0 >> 12);

    // stage Xs: x_proj rows l0-5 .. l0+134 (clamped), cols g0..g0+7  (140 x 16B)
    {
        const ushort* xpr = (const ushort*)xproj + (size_t)bidx * LL * CCH + g0;
        if (tid < 140) {
            int rr = min(max(l0 - 5 + tid, 0), LL - 1);
            *(short8*)(lds + XS_OFF + tid * 16) = *(const short8*)(xpr + (size_t)rr * CCH);
        }
        if (tid < 56) {   // kws[gg*7+k] = kwp[k*256 + g0+gg]
            int gg = tid / KK, k = tid % KK;
            ((float*)(lds + KW_OFF))[tid] = kwp[k * CCH + g0 + gg];
        }
    }

    const int srow = w * 32 + (lane >> 3);
    const int sgr  = (lane & 7) ^ ((lane >> 3) & 7);
    const __hip_bfloat16* a_src = A  + (m0 + srow) * 256 + sgr * 8;
    const __hip_bfloat16* b_src = Bt + (size_t)(n0 + srow) * 256 + sgr * 8;
    char* a_dst = As + (w * 32) * 128;
    char* b_dst = Bs + (w * 32) * 128;

    f32x4 acc[4][4] = {};

    for (int kt = 0; kt < 4; ++kt) {
        const int k0 = kt * 64;
        #pragma unroll
        for (int inst = 0; inst < 4; ++inst) {
            __builtin_amdgcn_global_load_lds((gvoid_t*)(a_src + k0 + (size_t)inst * 8 * 256),
                                             (svoid_t*)(a_dst + inst * 1024), 16, 0, 0);
            __builtin_amdgcn_global_load_lds((gvoid_t*)(b_src + k0 + (size_t)inst * 8 * 256),
                                             (svoid_t*)(b_dst + inst * 1024), 16, 0, 0);
        }
        __syncthreads();
        #pragma unroll
        for (int ks = 0; ks < 2; ++ks) {
            short8 a[4], b[4];
            #pragma unroll
            for (int i = 0; i < 4; ++i) {
                int mr = wr * 64 + i * 16 + (lane & 15);
                int gk = ks * 4 + (lane >> 4);
                a[i] = *(const short8*)(As + mr * 128 + ((gk ^ (mr & 7)) << 4));
                int nr = wc * 64 + i * 16 + (lane & 15);
                b[i] = *(const short8*)(Bs + nr * 128 + ((gk ^ (nr & 7)) << 4));
            }
            #pragma unroll
            for (int i = 0; i < 4; ++i)
                #pragma unroll
                for (int j = 0; j < 4; ++j)
                    acc[i][j] = __builtin_amdgcn_mfma_f32_16x16x32_bf16(a[i], b[j], acc[i][j], 0, 0, 0);
        }
        __syncthreads();
    }

    // epilogue 1: bias, tanh on off cols, store C tile to LDS as 2B (fp16 off / bf16 mask)
    ushort* Cs = (ushort*)lds;
    const int idclass = lane & 15;
    const bool is_off = idclass < 7;
    float reg_acc = 0.0f;
    #pragma unroll
    for (int j = 0; j < 4; ++j) {
        int col_l = wc * 64 + j * 16 + idclass;
        float bb = bias[n0 + col_l];
        #pragma unroll
        for (int i = 0; i < 4; ++i) {
            int row_l = wr * 64 + i * 16 + ((lane >> 4) << 2);
            f32x4 v = acc[i][j];
            #pragma unroll
            for (int q = 0; q < 4; ++q) {
                float val = v[q] + bb;
                ushort st;
                if (is_off) {
                    float xv = fminf(fmaxf(val, -15.0f), 15.0f);
                    float e2 = __expf(-2.0f * xv);
                    float ov = 2.0f * (1.0f - e2) / (1.0f + e2);   // 2*tanh
                    reg_acc += ov * ov;
                    __half hv = __float2half(ov);
                    st = *(ushort*)&hv;
                } else {
                    __hip_bfloat16 bv = __float2bfloat16(val);
                    st = *(ushort*)&bv;
                }
                Cs[(row_l + q) * CS_STRIDE + col_l] = st;
            }
        }
    }
    __syncthreads();

    // epilogue 2: per (row, g) point — gather taps, softmax over k, weighted sum
    const ushort* Xs = (const ushort*)(lds + XS_OFF);
    const float* kws = (const float*)(lds + KW_OFF);
    float ent_acc = 0.0f;
    #pragma unroll
    for (int pp = 0; pp < 4; ++pp) {
        int point = pp * 256 + tid;
        int r = point >> 3, gg = point & 7;
        const ushort* crow = Cs + r * CS_STRIDE + gg * 16;
        short8 c0 = *(const short8*)crow;
        short8 c1 = *(const short8*)(crow + 8);
        float mv[KK];
        float mx = -1e30f;
        #pragma unroll
        for (int k = 0; k < KK; ++k) { mv[k] = bf2f((ushort)c1[k]); mx = fmaxf(mx, mv[k]); }
        const int l = l0 + r;
        float es = 0.0f, tacc = 0.0f, o = 0.0f;
        #pragma unroll
        for (int k = 0; k < KK; ++k) {
            ushort ou = (ushort)c0[k];
            float ov = __half2float(*(const __half*)&ou);           // = 2*tanh(off)
            float p = (float)(l + k - 3) + ov;
            p = fminf(fmaxf(p, 0.0f), (float)(LL - 1));
            int pf = (int)p;
            float wcf = p - (float)pf;
            int ix  = pf - (l0 - 5);
            int ixc = min(pf + 1, LL - 1) - (l0 - 5);
            float sv = bf2f(Xs[ix * 8 + gg]) * (1.0f - wcf) + bf2f(Xs[ixc * 8 + gg]) * wcf;
            float d = mv[k] - mx;
            float e = __expf(d);
            es += e; tacc += e * d;
            o += sv * kws[gg * KK + k] * e;
        }
        float inv = 1.0f / es;
        ent_acc += tacc * inv - __logf(es);
        out_pre[(m0 + r) * CCH + g0 + gg] = __float2bfloat16(o * inv);
    }

    // reductions
    float* red = (float*)(lds + RED_OFF);
    red[tid] = reg_acc;
    __syncthreads();
    for (int s = 128; s > 0; s >>= 1) { if (tid < s) red[tid] += red[tid + s]; __syncthreads(); }
    if (tid == 0) atomicAdd(&accum[0], red[0]);
    __syncthreads();
    red[tid] = ent_acc;
    __syncthreads();
    for (int s = 128; s > 0; s >>= 1) { if (tid < s) red[tid] += red[tid + s]; __syncthreads(); }
    if (tid == 0) atomicAdd(&accum[1], red[0]);
}

// ---------------- finalize scalars ----------------
__global__ void finalize_kernel(const float* __restrict__ accum, float* __restrict__ out_tail)
{
    if (threadIdx.x == 0) {
        out_tail[0] = accum[0] / 29360128.0f;   // B*L*G*K
        out_tail[1] = accum[1] / 4194304.0f;    // B*L*G
    }
}

extern "C" void kernel_launch(void* const* d_in, const int* in_sizes, int n_in,
                              void* d_out, int out_size, void* d_ws, size_t ws_size,
                              hipStream_t stream)
{
    const float* x         = (const float*)d_in[0];
    const float* raw_sigma = (const float*)d_in[1];
    const float* w_in      = (const float*)d_in[2];
    const float* b_in      = (const float*)d_in[3];
    const float* w_out     = (const float*)d_in[4];
    const float* b_out     = (const float*)d_in[5];
    const float* dw1_w     = (const float*)d_in[6];
    const float* dw1_b     = (const float*)d_in[7];
    const float* dw2_w     = (const float*)d_in[8];
    const float* dw2_b     = (const float*)d_in[9];
    const float* w_off     = (const float*)d_in[10];
    const float* b_off     = (const float*)d_in[11];
    const float* w_mask    = (const float*)d_in[12];
    const float* b_mask    = (const float*)d_in[13];
    const float* k0w       = (const float*)d_in[14];
    const float* k0b       = (const float*)d_in[15];
    const float* k1w       = (const float*)d_in[16];
    const float* k1b       = (const float*)d_in[17];
    const float* k2w       = (const float*)d_in[18];
    const float* k2b       = (const float*)d_in[19];
    const float* k3w       = (const float*)d_in[20];
    const float* k3b       = (const float*)d_in[21];

    char* ws = (char*)d_ws;
    const size_t MB8 = (size_t)8 * 1024 * 1024;
    __hip_bfloat16* xbf    = (__hip_bfloat16*)(ws + 0);
    __hip_bfloat16* hbf    = (__hip_bfloat16*)(ws + MB8);        // h, reused as out_pre
    __hip_bfloat16* xdwbf  = (__hip_bfloat16*)(ws + 2 * MB8);
    __hip_bfloat16* xprojb = (__hip_bfloat16*)(ws + 3 * MB8);
    char* wbase = ws + 4 * MB8;
    __hip_bfloat16* wtin   = (__hip_bfloat16*)(wbase);                    // 128KB
    __hip_bfloat16* wtdw2  = (__hip_bfloat16*)(wbase + 131072);           // 128KB
    __hip_bfloat16* wtout  = (__hip_bfloat16*)(wbase + 262144);           // 128KB
    __hip_bfloat16* wtcomb = (__hip_bfloat16*)(wbase + 393216);           // 4096*256*2 = 2MB
    float* bcomb = (float*)(wbase + 393216 + 2097152);                    // 4096 floats
    float* kwp   = bcomb + NP;                                            // 1792 floats
    float* env   = kwp + NOFF;                                            // 7 (+pad)
    float* accum = env + 16;

    // 1) env / kernel weights (plane layout) / padded combined biases / zero accumulators
    precompute_kernel<<<1, 256, 0, stream>>>(raw_sigma, k0w, k0b, k1w, k1b,
                                             k2w, k2b, k3w, k3b, b_off, b_mask,
                                             kwp, bcomb, env, accum);
    // 2) weight transposes (off/mask -> padded g*16+idx layout, mask scaled by env)
    prep_kernel<<<dim3(112, 6), 256, 0, stream>>>(w_in, dw2_w, w_out, w_off, w_mask, env,
                                                  wtin, wtdw2, wtout, wtcomb);
    // 3) fused: xbf = bf16(x); h = silu(dwconv3(x) + dw1_b)
    dwconv_conv_kernel<<<(MTOT * CCH) / 1024, 256, 0, stream>>>(x, dw1_w, dw1_b, xbf, hbf);
    // 4) x_proj = x @ w_in + b_in   (bf16 out)
    gemm_bf16_k256<1><<<dim3(2, 128), 256, 0, stream>>>(xbf, wtin, b_in, xprojb, 256);
    // 5) x_dw = h @ dw2_w + dw2_b   (bf16 out)
    gemm_bf16_k256<1><<<dim3(2, 128), 256, 0, stream>>>(hbf, wtdw2, dw2_b, xdwbf, 256);
    // 6) fused off|mask GEMM + tanh + sampling + softmax  (out_pre -> hbf)
    gemm_fused_sample<<<dim3(NP / 128, MTOT / 128), 256, 0, stream>>>(
        xdwbf, wtcomb, bcomb, xprojb, kwp, hbf, accum);
    // 7) out = out_pre @ w_out + b_out  (fp32 out)
    gemm_bf16_k256<0><<<dim3(2, 128), 256, 0, stream>>>(hbf, wtout, b_out, (float*)d_out, 256);
    // 8) scalars
    finalize_kernel<<<1, 64, 0, stream>>>(accum, (float*)d_out + (size_t)MTOT * CCH);
}